// Round 4
// baseline (164.664 us; speedup 1.0000x reference)
//
#include <hip/hip_runtime.h>
#include <hip/hip_bf16.h>
#include <stdint.h>

// CKA loss via algebraic reduction:
//   HSIC_ij = ||Xi^T Xj||_F^2 - <d_i,d_j> - 2N<r_i,r_j> + N^2 t_i t_j
// Heavy part: 21 bf16-MFMA GEMMs [512x4096]x[4096x512], Frobenius-reduced.
//
// R4: (a) GEMM double-buffered LDS, ONE barrier per K-iter; prefetch of tile
// k+1 issued before compute of tile k, so the compiler's vmcnt(0) drain at
// the barrier lands after ~310 cyc of compute (R3 was latency-bound: all
// pipes <35%, 2 blk/CU). (b) X is read once, not twice: d[n] fused into the
// transpose, x.s computed from bf16 Xt (25 MB instead of 201 MB fp32);
// k_rowstats deleted. (c) transpose: transposed LDS tile [64][67] (odd
// stride -> <=2-way banks everywhere), 16-B global stores.

#define NPTS  4096
#define DF    512
#define ML    6
#define NPAIR 21
#define KSPLIT 8
#define KCHUNK (NPTS / KSPLIT)   // 512

typedef __bf16 bf16_t;
typedef bf16_t bf16x8 __attribute__((ext_vector_type(8)));
typedef float  f32x4  __attribute__((ext_vector_type(4)));
typedef unsigned short u16;
typedef u16 u16x8 __attribute__((ext_vector_type(8)));

__constant__ int c_PI[NPAIR] = {0,0,0,0,0,0, 1,1,1,1,1, 2,2,2,2, 3,3,3, 4,4, 5};
__constant__ int c_PJ[NPAIR] = {0,1,2,3,4,5, 1,2,3,4,5, 2,3,4,5, 3,4,5, 4,5, 5};

// ---- workspace layout (bytes) ----
#define OFF_XT 0u                        // 6*512*4096*2 = 25165824
#define OFF_S  25165824u                 // 6*512*4 = 12288        (zeroed)
#define OFF_F  (OFF_S + 12288u)          // 21*4 pad 512           (zeroed)
#define OFF_D  (OFF_F + 512u)            // 6*4096*4 = 98304       (zeroed)
#define OFF_XS (OFF_D + 98304u)          // 98304                  (zeroed)
#define ZERO_BYTES (12288u + 512u + 98304u + 98304u)
#define OFF_DD (OFF_XS + 98304u)         // 256
#define OFF_RD (OFF_DD + 256u)           // 256
#define OFF_T  (OFF_RD + 256u)           // 256

__device__ __forceinline__ u16 f2bf(float x) {
    union { float f; unsigned u; } v; v.f = x;
    unsigned r = v.u + 0x7fffu + ((v.u >> 16) & 1u);   // RNE
    return (u16)(r >> 16);
}
__device__ __forceinline__ float bf2f(u16 h) {
    union { unsigned u; float f; } v; v.u = ((unsigned)h) << 16; return v.f;
}

__device__ __forceinline__ void gl2lds16(const void* g, void* l) {
    __builtin_amdgcn_global_load_lds(
        (__attribute__((address_space(1))) void*)g,
        (__attribute__((address_space(3))) void*)l, 16, 0, 0);
}

// ------- K1: transpose + fp32->bf16 + col sums s + row sq-sums d -------------
// X[l][n][d] -> Xt[l][d][n]. LDS tile is already transposed: tT[d][n], odd
// leading stride 67 keeps every scalar LDS access <=2-way (free).
__global__ __launch_bounds__(256) void k_transpose(const float* __restrict__ X,
                                                   u16* __restrict__ Xt,
                                                   float* __restrict__ s,
                                                   float* __restrict__ dv) {
    __shared__ float tT[64][67];
    int l = blockIdx.z, n0 = blockIdx.x * 64, d0 = blockIdx.y * 64;
    int t = threadIdx.x, q = t & 15, r = t >> 4;           // q: d-quad, r: n-row
    const float4* src = (const float4*)(X + ((size_t)l * NPTS + n0) * DF + d0);
#pragma unroll
    for (int p = 0; p < 4; ++p) {
        int rr = r + 16 * p;
        float4 v = src[(size_t)rr * (DF / 4) + q];
        tT[4 * q + 0][rr] = v.x;
        tT[4 * q + 1][rr] = v.y;
        tT[4 * q + 2][rr] = v.z;
        tT[4 * q + 3][rr] = v.w;
    }
    __syncthreads();
    if (t < 64) {                        // column sums over n (d = t)
        float cs = 0.f;
#pragma unroll
        for (int k = 0; k < 64; ++k) {
            int n = (6 * t + k) & 63;    // rotation -> 2-way banks
            cs += tT[t][n];
        }
        atomicAdd(&s[l * DF + d0 + t], cs);
    } else if (t < 128) {                // row sums of squares over d (n = t-64)
        int n = t - 64;
        float rs = 0.f;
#pragma unroll
        for (int d = 0; d < 64; ++d) { float v = tT[d][n]; rs += v * v; }
        atomicAdd(&dv[l * NPTS + n0 + n], rs);
    }
    // write phase (all 256 threads): 2 passes x 16B stores
#pragma unroll
    for (int pp = 0; pp < 2; ++pp) {
        int dcol = (t >> 3) + 32 * pp, n8 = (t & 7) * 8;
        u16x8 o;
#pragma unroll
        for (int j = 0; j < 8; ++j) o[j] = f2bf(tT[dcol][n8 + j]);
        *(u16x8*)(Xt + ((size_t)(l * DF + d0 + dcol)) * NPTS + n0 + n8) = o;
    }
}

// ---------------- K2: xs[l][n] = X[l] @ s[l], from bf16 Xt -------------------
// grid (4, 8, 6): x = n-chunk of 1024 (4 n/thread), y = d-chunk of 64, z = l.
__global__ __launch_bounds__(256) void k_rowdot(const u16* __restrict__ Xt,
                                                const float* __restrict__ s,
                                                float* __restrict__ xs) {
    int l = blockIdx.z, d0 = blockIdx.y * 64, n0 = blockIdx.x * 1024;
    int t = threadIdx.x;
    __shared__ float sl[64];
    if (t < 64) sl[t] = s[l * DF + d0 + t];
    __syncthreads();
    const u16* base = Xt + ((size_t)(l * DF + d0)) * NPTS + n0 + t * 4;
    float a0 = 0, a1 = 0, a2 = 0, a3 = 0;
#pragma unroll 8
    for (int d = 0; d < 64; ++d) {
        ushort4 v = *(const ushort4*)(base + (size_t)d * NPTS);
        float sv = sl[d];
        a0 += sv * bf2f(v.x); a1 += sv * bf2f(v.y);
        a2 += sv * bf2f(v.z); a3 += sv * bf2f(v.w);
    }
    float* o = xs + l * NPTS + n0 + t * 4;
    atomicAdd(&o[0], a0); atomicAdd(&o[1], a1);
    atomicAdd(&o[2], a2); atomicAdd(&o[3], a3);
}

// ---------------- K4: pair dots <d_i,d_j>, <r_i,r_j>, and t_i ----------------
__global__ __launch_bounds__(256) void k_pairdots(const float* __restrict__ dv,
                                                  const float* __restrict__ xs,
                                                  const float* __restrict__ s,
                                                  float* __restrict__ ddot,
                                                  float* __restrict__ rdot,
                                                  float* __restrict__ tb) {
    int p = blockIdx.x, i = c_PI[p], j = c_PJ[p];
    int t = threadIdx.x;
    const float invN = 1.0f / (float)NPTS;
    float dd = 0.f, rr = 0.f, sd = 0.f, ss = 0.f;
    for (int n = t; n < NPTS; n += 256) {
        float di = dv[i * NPTS + n], dj = dv[j * NPTS + n];
        float ri = (xs[i * NPTS + n] - di) * invN;
        float rj = (xs[j * NPTS + n] - dj) * invN;
        dd += di * dj;
        rr += ri * rj;
        sd += di;
    }
    for (int c = t; c < DF; c += 256) { float v = s[i * DF + c]; ss += v * v; }
    __shared__ float4 red[256];
    red[t] = make_float4(dd, rr, sd, ss);
    __syncthreads();
    for (int h = 128; h > 0; h >>= 1) {
        if (t < h) {
            float4 a = red[t], b = red[t + h];
            red[t] = make_float4(a.x + b.x, a.y + b.y, a.z + b.z, a.w + b.w);
        }
        __syncthreads();
    }
    if (t == 0) {
        ddot[p] = red[0].x;
        rdot[p] = red[0].y;
        if (i == j)
            tb[i] = (red[0].w - red[0].z) * (1.0f / ((float)NPTS * (float)NPTS));
    }
}

// ---------------- K5: bf16 MFMA GEMM + Frobenius reduce (split-K, dbuf) ------
// grid (8, 21, 8): x = (mi 4)x(nj 2) tile of 512x512 C, y = pair, z = K/512.
// Block 128x256, 4 waves; wave tile 64x128 (4x8 of 16x16x32 MFMA), BK=32.
// Double-buffered: barrier -> prefetch(it+1) -> compute(it). The vmcnt(0)
// drain at the barrier then overlaps the previous iteration's compute.
__device__ __forceinline__ void stage_tile(const u16* A, const u16* B,
                                           u16* As, u16* Bs, int k0,
                                           int wave, int rl, int g) {
#pragma unroll
    for (int is = 0; is < 2; ++is) {                       // A: 128 rows
        int rbase = is * 64 + wave * 16;                   // wave-uniform
        int r = rbase + rl;
        int gs = g ^ ((r >> 1) & 3);                       // XOR swizzle
        gl2lds16(A + (size_t)r * NPTS + k0 + gs * 8, As + rbase * 32);
    }
#pragma unroll
    for (int is = 0; is < 4; ++is) {                       // B: 256 rows
        int rbase = is * 64 + wave * 16;
        int r = rbase + rl;
        int gs = g ^ ((r >> 1) & 3);
        gl2lds16(B + (size_t)r * NPTS + k0 + gs * 8, Bs + rbase * 32);
    }
}

__global__ __launch_bounds__(256, 2) void k_gemm_frob(const u16* __restrict__ Xt,
                                                      float* __restrict__ F) {
    int p = blockIdx.y;
    int aBase = (blockIdx.x & 3) * 128;
    int bBase = (blockIdx.x >> 2) * 256;
    int kLo = blockIdx.z * KCHUNK;
    const u16* A = Xt + ((size_t)(c_PI[p] * DF + aBase)) * NPTS;
    const u16* B = Xt + ((size_t)(c_PJ[p] * DF + bBase)) * NPTS;

    __shared__ __align__(16) u16 As[2][128 * 32];          // 2 x  8 KB
    __shared__ __align__(16) u16 Bs[2][256 * 32];          // 2 x 16 KB

    int t = threadIdx.x, wave = t >> 6, lane = t & 63;
    int rl = lane >> 2, g = lane & 3;          // staging: row-in-16, 16B group
    int wr = (wave >> 1) * 64, wc = (wave & 1) * 128;
    int row16 = lane & 15, quad = lane >> 4;   // MFMA fragment indices

    f32x4 acc[4][8];
#pragma unroll
    for (int mi = 0; mi < 4; ++mi)
#pragma unroll
        for (int ni = 0; ni < 8; ++ni) acc[mi][ni] = (f32x4)0.0f;

    stage_tile(A, B, As[0], Bs[0], kLo, wave, rl, g);      // prologue prefetch

    const int NIT = KCHUNK / 32;                           // 16
    for (int it = 0; it < NIT; ++it) {
        int cur = it & 1;
        __syncthreads();   // drains vmcnt: tile 'it' visible; prev ds_reads done
        if (it + 1 < NIT)
            stage_tile(A, B, As[cur ^ 1], Bs[cur ^ 1],
                       kLo + (it + 1) * 32, wave, rl, g);

        bf16x8 af[4], bf[8];
#pragma unroll
        for (int mi = 0; mi < 4; ++mi) {
            int row = wr + mi * 16 + row16;
            int gg = quad ^ ((row >> 1) & 3);
            af[mi] = *(const bf16x8*)&As[cur][row * 32 + gg * 8];
        }
#pragma unroll
        for (int ni = 0; ni < 8; ++ni) {
            int row = wc + ni * 16 + row16;
            int gg = quad ^ ((row >> 1) & 3);
            bf[ni] = *(const bf16x8*)&Bs[cur][row * 32 + gg * 8];
        }
#pragma unroll
        for (int mi = 0; mi < 4; ++mi)
#pragma unroll
            for (int ni = 0; ni < 8; ++ni)
                acc[mi][ni] = __builtin_amdgcn_mfma_f32_16x16x32_bf16(
                    af[mi], bf[ni], acc[mi][ni], 0, 0, 0);
    }

    // Frobenius reduce (layout-agnostic: every acc element counted once)
    float local = 0.f;
#pragma unroll
    for (int mi = 0; mi < 4; ++mi)
#pragma unroll
        for (int ni = 0; ni < 8; ++ni)
#pragma unroll
            for (int e = 0; e < 4; ++e)
                local += acc[mi][ni][e] * acc[mi][ni][e];
    for (int off = 32; off; off >>= 1) local += __shfl_down(local, off);
    __shared__ float wsum[4];
    if (lane == 0) wsum[wave] = local;
    __syncthreads();
    if (t == 0) atomicAdd(&F[p], wsum[0] + wsum[1] + wsum[2] + wsum[3]);
}

// ---------------- K6: finalize -> hsic_visual (36) + l (1) -------------------
__global__ __launch_bounds__(64) void k_finalize(const float* __restrict__ F,
                                                 const float* __restrict__ ddot,
                                                 const float* __restrict__ rdot,
                                                 const float* __restrict__ tb,
                                                 float* __restrict__ out) {
    __shared__ double hs[ML][ML];
    __shared__ float cka[ML][ML];
    int t = threadIdx.x;
    if (t < NPAIR) {
        int i = c_PI[t], j = c_PJ[t];
        double v = (double)F[t] - (double)ddot[t]
                 - 2.0 * (double)NPTS * (double)rdot[t]
                 + (double)NPTS * (double)NPTS * (double)tb[i] * (double)tb[j];
        hs[i][j] = v; hs[j][i] = v;
    }
    __syncthreads();
    if (t < ML * ML) {
        int i = t / ML, j = t % ML;
        float v;
        if (i == j) v = 1.0f;
        else v = (float)(fabs(hs[i][j]) / sqrt(hs[i][i] * hs[j][j] + 1e-6));
        cka[i][j] = v;
        out[t] = v;
    }
    __syncthreads();
    if (t == 0) {
        float l = 0.f;
        for (int i = 1; i < ML; ++i)
            for (int j = 0; j < i; ++j) l += cka[i][j];   // cka >= 0
        out[ML * ML] = l;
    }
}

extern "C" void kernel_launch(void* const* d_in, const int* in_sizes, int n_in,
                              void* d_out, int out_size, void* d_ws, size_t ws_size,
                              hipStream_t stream) {
    (void)in_sizes; (void)n_in; (void)out_size; (void)ws_size;
    const float* X = (const float*)d_in[0];
    float* out = (float*)d_out;
    char* ws = (char*)d_ws;
    u16*   Xt = (u16*)(ws + OFF_XT);
    float* s  = (float*)(ws + OFF_S);
    float* F  = (float*)(ws + OFF_F);
    float* dv = (float*)(ws + OFF_D);
    float* xs = (float*)(ws + OFF_XS);
    float* dd = (float*)(ws + OFF_DD);
    float* rd = (float*)(ws + OFF_RD);
    float* tb = (float*)(ws + OFF_T);

    hipMemsetAsync(ws + OFF_S, 0, ZERO_BYTES, stream);     // zero s,F,dv,xs

    hipLaunchKernelGGL(k_transpose, dim3(64, 8, 6), dim3(256), 0, stream, X, Xt, s, dv);
    hipLaunchKernelGGL(k_gemm_frob, dim3(8, NPAIR, KSPLIT), dim3(256), 0, stream, Xt, F);
    hipLaunchKernelGGL(k_rowdot,    dim3(4, 8, 6),  dim3(256), 0, stream, Xt, s, xs);
    hipLaunchKernelGGL(k_pairdots,  dim3(NPAIR),    dim3(256), 0, stream, dv, xs, s, dd, rd, tb);
    hipLaunchKernelGGL(k_finalize,  dim3(1),        dim3(64),  0, stream, F, dd, rd, tb, out);
}

// Round 5
// 152.778 us; speedup vs baseline: 1.0778x; 1.0778x over previous
//
#include <hip/hip_runtime.h>
#include <hip/hip_bf16.h>
#include <stdint.h>

// CKA loss via algebraic reduction:
//   HSIC_ij = ||Xi^T Xj||_F^2 - <d_i,d_j> - 2N<r_i,r_j> + N^2 t_i t_j
// Heavy part: 21 bf16-MFMA GEMMs [512x4096]x[4096x512], Frobenius-reduced.
//
// R5: K-loop is latency-event-bound (~3300 cyc/iter vs ~300 cyc pipe work;
// R4 dbuf gave only 1-iter cover and regressed -> reverted). Instead halve
// the number of latency events: BK 32 -> 64 (8 iters instead of 16).
// Free: we are register-bound at 2 blocks/CU, and 2 x 48 KB LDS < 160 KB.
// Single-buffer 2-barrier structure (R3-proven), 8-group XOR swizzle.

#define NPTS  4096
#define DF    512
#define ML    6
#define NPAIR 21
#define KSPLIT 8
#define KCHUNK (NPTS / KSPLIT)   // 512
#define BK    64

typedef __bf16 bf16_t;
typedef bf16_t bf16x8 __attribute__((ext_vector_type(8)));
typedef float  f32x4  __attribute__((ext_vector_type(4)));
typedef unsigned short u16;
typedef u16 u16x8 __attribute__((ext_vector_type(8)));

__constant__ int c_PI[NPAIR] = {0,0,0,0,0,0, 1,1,1,1,1, 2,2,2,2, 3,3,3, 4,4, 5};
__constant__ int c_PJ[NPAIR] = {0,1,2,3,4,5, 1,2,3,4,5, 2,3,4,5, 3,4,5, 4,5, 5};

// ---- workspace layout (bytes) ----
#define OFF_XT 0u                        // 6*512*4096*2 = 25165824
#define OFF_S  25165824u                 // 6*512*4 = 12288        (zeroed)
#define OFF_F  (OFF_S + 12288u)          // 21*4 pad 512           (zeroed)
#define OFF_D  (OFF_F + 512u)            // 6*4096*4 = 98304       (zeroed)
#define OFF_XS (OFF_D + 98304u)          // 98304                  (zeroed)
#define ZERO_BYTES (12288u + 512u + 98304u + 98304u)
#define OFF_DD (OFF_XS + 98304u)         // 256
#define OFF_RD (OFF_DD + 256u)           // 256
#define OFF_T  (OFF_RD + 256u)           // 256

__device__ __forceinline__ u16 f2bf(float x) {
    union { float f; unsigned u; } v; v.f = x;
    unsigned r = v.u + 0x7fffu + ((v.u >> 16) & 1u);   // RNE
    return (u16)(r >> 16);
}
__device__ __forceinline__ float bf2f(u16 h) {
    union { unsigned u; float f; } v; v.u = ((unsigned)h) << 16; return v.f;
}

__device__ __forceinline__ void gl2lds16(const void* g, void* l) {
    __builtin_amdgcn_global_load_lds(
        (__attribute__((address_space(1))) void*)g,
        (__attribute__((address_space(3))) void*)l, 16, 0, 0);
}

// ------- K1: transpose + fp32->bf16 + col sums s + row sq-sums d -------------
// X[l][n][d] -> Xt[l][d][n]. LDS tile is already transposed: tT[d][n], odd
// leading stride 67 keeps every scalar LDS access <=2-way (free).
__global__ __launch_bounds__(256) void k_transpose(const float* __restrict__ X,
                                                   u16* __restrict__ Xt,
                                                   float* __restrict__ s,
                                                   float* __restrict__ dv) {
    __shared__ float tT[64][67];
    int l = blockIdx.z, n0 = blockIdx.x * 64, d0 = blockIdx.y * 64;
    int t = threadIdx.x, q = t & 15, r = t >> 4;           // q: d-quad, r: n-row
    const float4* src = (const float4*)(X + ((size_t)l * NPTS + n0) * DF + d0);
#pragma unroll
    for (int p = 0; p < 4; ++p) {
        int rr = r + 16 * p;
        float4 v = src[(size_t)rr * (DF / 4) + q];
        tT[4 * q + 0][rr] = v.x;
        tT[4 * q + 1][rr] = v.y;
        tT[4 * q + 2][rr] = v.z;
        tT[4 * q + 3][rr] = v.w;
    }
    __syncthreads();
    if (t < 64) {                        // column sums over n (d = t)
        float cs = 0.f;
#pragma unroll
        for (int k = 0; k < 64; ++k) {
            int n = (6 * t + k) & 63;    // rotation -> 2-way banks
            cs += tT[t][n];
        }
        atomicAdd(&s[l * DF + d0 + t], cs);
    } else if (t < 128) {                // row sums of squares over d (n = t-64)
        int n = t - 64;
        float rs = 0.f;
#pragma unroll
        for (int d = 0; d < 64; ++d) { float v = tT[d][n]; rs += v * v; }
        atomicAdd(&dv[l * NPTS + n0 + n], rs);
    }
    // write phase (all 256 threads): 2 passes x 16B stores
#pragma unroll
    for (int pp = 0; pp < 2; ++pp) {
        int dcol = (t >> 3) + 32 * pp, n8 = (t & 7) * 8;
        u16x8 o;
#pragma unroll
        for (int j = 0; j < 8; ++j) o[j] = f2bf(tT[dcol][n8 + j]);
        *(u16x8*)(Xt + ((size_t)(l * DF + d0 + dcol)) * NPTS + n0 + n8) = o;
    }
}

// ---------------- K2: xs[l][n] = X[l] @ s[l], from bf16 Xt -------------------
__global__ __launch_bounds__(256) void k_rowdot(const u16* __restrict__ Xt,
                                                const float* __restrict__ s,
                                                float* __restrict__ xs) {
    int l = blockIdx.z, d0 = blockIdx.y * 64, n0 = blockIdx.x * 1024;
    int t = threadIdx.x;
    __shared__ float sl[64];
    if (t < 64) sl[t] = s[l * DF + d0 + t];
    __syncthreads();
    const u16* base = Xt + ((size_t)(l * DF + d0)) * NPTS + n0 + t * 4;
    float a0 = 0, a1 = 0, a2 = 0, a3 = 0;
#pragma unroll 8
    for (int d = 0; d < 64; ++d) {
        ushort4 v = *(const ushort4*)(base + (size_t)d * NPTS);
        float sv = sl[d];
        a0 += sv * bf2f(v.x); a1 += sv * bf2f(v.y);
        a2 += sv * bf2f(v.z); a3 += sv * bf2f(v.w);
    }
    float* o = xs + l * NPTS + n0 + t * 4;
    atomicAdd(&o[0], a0); atomicAdd(&o[1], a1);
    atomicAdd(&o[2], a2); atomicAdd(&o[3], a3);
}

// ---------------- K4: pair dots <d_i,d_j>, <r_i,r_j>, and t_i ----------------
__global__ __launch_bounds__(256) void k_pairdots(const float* __restrict__ dv,
                                                  const float* __restrict__ xs,
                                                  const float* __restrict__ s,
                                                  float* __restrict__ ddot,
                                                  float* __restrict__ rdot,
                                                  float* __restrict__ tb) {
    int p = blockIdx.x, i = c_PI[p], j = c_PJ[p];
    int t = threadIdx.x;
    const float invN = 1.0f / (float)NPTS;
    float dd = 0.f, rr = 0.f, sd = 0.f, ss = 0.f;
    for (int n = t; n < NPTS; n += 256) {
        float di = dv[i * NPTS + n], dj = dv[j * NPTS + n];
        float ri = (xs[i * NPTS + n] - di) * invN;
        float rj = (xs[j * NPTS + n] - dj) * invN;
        dd += di * dj;
        rr += ri * rj;
        sd += di;
    }
    for (int c = t; c < DF; c += 256) { float v = s[i * DF + c]; ss += v * v; }
    __shared__ float4 red[256];
    red[t] = make_float4(dd, rr, sd, ss);
    __syncthreads();
    for (int h = 128; h > 0; h >>= 1) {
        if (t < h) {
            float4 a = red[t], b = red[t + h];
            red[t] = make_float4(a.x + b.x, a.y + b.y, a.z + b.z, a.w + b.w);
        }
        __syncthreads();
    }
    if (t == 0) {
        ddot[p] = red[0].x;
        rdot[p] = red[0].y;
        if (i == j)
            tb[i] = (red[0].w - red[0].z) * (1.0f / ((float)NPTS * (float)NPTS));
    }
}

// ---------------- K5: bf16 MFMA GEMM + Frobenius reduce (split-K, BK=64) -----
// grid (8, 21, 8): x = (mi 4)x(nj 2) tile of 512x512 C, y = pair, z = K/512.
// Block 128x256, 4 waves; wave tile 64x128 (4x8 of 16x16x32 MFMA).
// LDS row stride 64 u16 = 128 B; 8 x 16B groups, XOR-swizzled by (row&7).
__global__ __launch_bounds__(256, 2) void k_gemm_frob(const u16* __restrict__ Xt,
                                                      float* __restrict__ F) {
    int p = blockIdx.y;
    int aBase = (blockIdx.x & 3) * 128;
    int bBase = (blockIdx.x >> 2) * 256;
    int kLo = blockIdx.z * KCHUNK, kHi = kLo + KCHUNK;
    const u16* A = Xt + ((size_t)(c_PI[p] * DF + aBase)) * NPTS;
    const u16* B = Xt + ((size_t)(c_PJ[p] * DF + bBase)) * NPTS;

    __shared__ __align__(16) u16 As[128 * BK];             // 16 KB
    __shared__ __align__(16) u16 Bs[256 * BK];             // 32 KB

    int t = threadIdx.x, wave = t >> 6, lane = t & 63;
    int rl = lane >> 3, g = lane & 7;          // staging: row-in-8, 16B group
    int wr = (wave >> 1) * 64, wc = (wave & 1) * 128;
    int row16 = lane & 15, quad = lane >> 4;   // MFMA fragment indices

    f32x4 acc[4][8];
#pragma unroll
    for (int mi = 0; mi < 4; ++mi)
#pragma unroll
        for (int ni = 0; ni < 8; ++ni) acc[mi][ni] = (f32x4)0.0f;

    for (int k0 = kLo; k0 < kHi; k0 += BK) {
        __syncthreads();   // previous iter's ds_reads done before DMA overwrite
#pragma unroll
        for (int is = 0; is < 4; ++is) {                   // A: 128 rows
            int rbase = is * 32 + wave * 8;                // wave-uniform
            int r = rbase + rl;
            int gs = g ^ (r & 7);                          // XOR swizzle (8 grp)
            gl2lds16(A + (size_t)r * NPTS + k0 + gs * 8, &As[rbase * BK]);
        }
#pragma unroll
        for (int is = 0; is < 8; ++is) {                   // B: 256 rows
            int rbase = is * 32 + wave * 8;
            int r = rbase + rl;
            int gs = g ^ (r & 7);
            gl2lds16(B + (size_t)r * NPTS + k0 + gs * 8, &Bs[rbase * BK]);
        }
        __syncthreads();   // vmcnt(0) drained at barrier -> LDS valid

#pragma unroll
        for (int ko = 0; ko < 2; ++ko) {                   // two 32-k steps
            bf16x8 af[4], bf[8];
#pragma unroll
            for (int mi = 0; mi < 4; ++mi) {
                int row = wr + mi * 16 + row16;
                int gg = (ko * 4 + quad) ^ (row & 7);
                af[mi] = *(const bf16x8*)&As[row * BK + gg * 8];
            }
#pragma unroll
            for (int ni = 0; ni < 8; ++ni) {
                int row = wc + ni * 16 + row16;
                int gg = (ko * 4 + quad) ^ (row & 7);
                bf[ni] = *(const bf16x8*)&Bs[row * BK + gg * 8];
            }
#pragma unroll
            for (int mi = 0; mi < 4; ++mi)
#pragma unroll
                for (int ni = 0; ni < 8; ++ni)
                    acc[mi][ni] = __builtin_amdgcn_mfma_f32_16x16x32_bf16(
                        af[mi], bf[ni], acc[mi][ni], 0, 0, 0);
        }
    }

    // Frobenius reduce (layout-agnostic: every acc element counted once)
    float local = 0.f;
#pragma unroll
    for (int mi = 0; mi < 4; ++mi)
#pragma unroll
        for (int ni = 0; ni < 8; ++ni)
#pragma unroll
            for (int e = 0; e < 4; ++e)
                local += acc[mi][ni][e] * acc[mi][ni][e];
    for (int off = 32; off; off >>= 1) local += __shfl_down(local, off);
    __shared__ float wsum[4];
    if (lane == 0) wsum[wave] = local;
    __syncthreads();
    if (t == 0) atomicAdd(&F[p], wsum[0] + wsum[1] + wsum[2] + wsum[3]);
}

// ---------------- K6: finalize -> hsic_visual (36) + l (1) -------------------
__global__ __launch_bounds__(64) void k_finalize(const float* __restrict__ F,
                                                 const float* __restrict__ ddot,
                                                 const float* __restrict__ rdot,
                                                 const float* __restrict__ tb,
                                                 float* __restrict__ out) {
    __shared__ double hs[ML][ML];
    __shared__ float cka[ML][ML];
    int t = threadIdx.x;
    if (t < NPAIR) {
        int i = c_PI[t], j = c_PJ[t];
        double v = (double)F[t] - (double)ddot[t]
                 - 2.0 * (double)NPTS * (double)rdot[t]
                 + (double)NPTS * (double)NPTS * (double)tb[i] * (double)tb[j];
        hs[i][j] = v; hs[j][i] = v;
    }
    __syncthreads();
    if (t < ML * ML) {
        int i = t / ML, j = t % ML;
        float v;
        if (i == j) v = 1.0f;
        else v = (float)(fabs(hs[i][j]) / sqrt(hs[i][i] * hs[j][j] + 1e-6));
        cka[i][j] = v;
        out[t] = v;
    }
    __syncthreads();
    if (t == 0) {
        float l = 0.f;
        for (int i = 1; i < ML; ++i)
            for (int j = 0; j < i; ++j) l += cka[i][j];   // cka >= 0
        out[ML * ML] = l;
    }
}

extern "C" void kernel_launch(void* const* d_in, const int* in_sizes, int n_in,
                              void* d_out, int out_size, void* d_ws, size_t ws_size,
                              hipStream_t stream) {
    (void)in_sizes; (void)n_in; (void)out_size; (void)ws_size;
    const float* X = (const float*)d_in[0];
    float* out = (float*)d_out;
    char* ws = (char*)d_ws;
    u16*   Xt = (u16*)(ws + OFF_XT);
    float* s  = (float*)(ws + OFF_S);
    float* F  = (float*)(ws + OFF_F);
    float* dv = (float*)(ws + OFF_D);
    float* xs = (float*)(ws + OFF_XS);
    float* dd = (float*)(ws + OFF_DD);
    float* rd = (float*)(ws + OFF_RD);
    float* tb = (float*)(ws + OFF_T);

    hipMemsetAsync(ws + OFF_S, 0, ZERO_BYTES, stream);     // zero s,F,dv,xs

    hipLaunchKernelGGL(k_transpose, dim3(64, 8, 6), dim3(256), 0, stream, X, Xt, s, dv);
    hipLaunchKernelGGL(k_gemm_frob, dim3(8, NPAIR, KSPLIT), dim3(256), 0, stream, Xt, F);
    hipLaunchKernelGGL(k_rowdot,    dim3(4, 8, 6),  dim3(256), 0, stream, Xt, s, xs);
    hipLaunchKernelGGL(k_pairdots,  dim3(NPAIR),    dim3(256), 0, stream, dv, xs, s, dd, rd, tb);
    hipLaunchKernelGGL(k_finalize,  dim3(1),        dim3(64),  0, stream, F, dd, rd, tb, out);
}